// Round 5
// baseline (512.911 us; speedup 1.0000x reference)
//
#include <hip/hip_runtime.h>

// Problem constants (match reference)
#define NN 100000
#define TT 128
#define EE 1600000
#define KK 9
#define PADK 4

// Binned CSR build
#define BSH 9                     // 512 nodes per bucket
#define BMASK 511
#define NBUCK 196                 // ceil(100000/512)
#define BCAP 10240                // avg 8163/bucket, sigma~90 -> 23 sigma headroom
#define BINB 782                  // (EE + 2047) / 2048
#define CVTB 12500                // NN*TT/4 / 256

// Output head
#define OCH 512                   // nodes per block
#define ONB 196                   // ceil(NN/OCH)

typedef _Float16 f16;
typedef __attribute__((ext_vector_type(2))) _Float16 f16x2;
typedef __attribute__((ext_vector_type(4))) _Float16 f16x4;
typedef __attribute__((ext_vector_type(8))) _Float16 f16x8;

union HU8 { f16x8 h; int4 i; };

// ---------- fused: bin edges by dst range (blocks 0..BINB) + x fp32->fp16 (rest) ----------
// Packed edge: (dlocal << 20) | src   (src < 2^17, dlocal < 2^9)
__global__ void bin_cvt_kernel(const int* __restrict__ ei, int* __restrict__ gcursor,
                               unsigned int* __restrict__ binned,
                               const float4* __restrict__ x, f16x4* __restrict__ x16) {
    __shared__ int hist[NBUCK];
    __shared__ int gbase[NBUCK];
    int tid = threadIdx.x;

    if (blockIdx.x >= BINB) {
        // cvt part: one float4 per thread over N*T/4 (exactly CVTB*256 elements)
        int i = (blockIdx.x - BINB) * 256 + tid;
        float4 v = x[i];
        f16x4 o;
        o.x = (f16)v.x; o.y = (f16)v.y; o.z = (f16)v.z; o.w = (f16)v.w;
        x16[i] = o;
        return;
    }

    for (int i = tid; i < NBUCK; i += 256) hist[i] = 0;
    __syncthreads();
    int base = blockIdx.x * 2048;
    unsigned int val[8];
    int bkt[8];
    int rank[8];
#pragma unroll
    for (int k = 0; k < 8; k++) {
        int e = base + k * 256 + tid;
        bkt[k] = -1;
        if (e < EE) {
            int s = ei[e];            // src
            int d = ei[EE + e];       // dst
            bkt[k] = d >> BSH;
            val[k] = ((unsigned int)(d & BMASK) << 20) | (unsigned int)s;
            rank[k] = atomicAdd(&hist[bkt[k]], 1);
        }
    }
    __syncthreads();
    for (int i = tid; i < NBUCK; i += 256)
        gbase[i] = hist[i] ? atomicAdd(&gcursor[i], hist[i]) : 0;
    __syncthreads();
#pragma unroll
    for (int k = 0; k < 8; k++) {
        if (bkt[k] >= 0)
            binned[(size_t)bkt[k] * BCAP + gbase[bkt[k]] + rank[k]] = val[k];
    }
}

// ---------- per-bucket: scan bucket bases + hist + node scan + offsets/inv_cnt + place ----------
__global__ void bucket_csr_kernel(const unsigned int* __restrict__ binned,
                                  const int* __restrict__ gcursor,
                                  int* __restrict__ offsets,
                                  float* __restrict__ inv_cnt,
                                  int* __restrict__ col) {
    __shared__ int hist[512];
    __shared__ int cur[512];
    __shared__ int sm[256];
    int b = blockIdx.x;
    int tid = threadIdx.x;

    // bucket-base scan over all 196 bucket counts (each block redoes it; ~µs)
    sm[tid] = (tid < NBUCK) ? gcursor[tid] : 0;
    __syncthreads();
    for (int off = 1; off < 256; off <<= 1) {
        int v = (tid >= off) ? sm[tid - off] : 0;
        __syncthreads();
        sm[tid] += v;
        __syncthreads();
    }
    int bucket_base = (b == 0) ? 0 : sm[b - 1];
    if (b == 0 && tid == 0) offsets[NN] = EE;

    int cnt = gcursor[b];
    const unsigned int* ePtr = binned + (size_t)b * BCAP;
    hist[tid] = 0;
    hist[tid + 256] = 0;
    __syncthreads();
    for (int j = tid; j < cnt; j += 256)
        atomicAdd(&hist[ePtr[j] >> 20], 1);
    __syncthreads();
    // exclusive scan of 512 degree counts (thread t owns entries 2t, 2t+1)
    int d0 = hist[2 * tid], d1 = hist[2 * tid + 1];
    sm[tid] = d0 + d1;
    __syncthreads();
    for (int off = 1; off < 256; off <<= 1) {
        int v = (tid >= off) ? sm[tid - off] : 0;
        __syncthreads();
        sm[tid] += v;
        __syncthreads();
    }
    int basep = bucket_base + ((tid == 0) ? 0 : sm[tid - 1]);
    int node0 = (b << BSH) + 2 * tid;
    int p0 = basep;
    int p1 = basep + d0;
    if (node0 < NN) {
        offsets[node0] = p0;
        inv_cnt[node0] = 1.0f / (1.0f + (float)d0);
        cur[2 * tid] = p0;
    }
    if (node0 + 1 < NN) {
        offsets[node0 + 1] = p1;
        inv_cnt[node0 + 1] = 1.0f / (1.0f + (float)d1);
        cur[2 * tid + 1] = p1;
    }
    __syncthreads();
    // place: all writes land in this bucket's contiguous col window (~32 KB, L2-resident)
    for (int j = tid; j < cnt; j += 256) {
        unsigned int v = ePtr[j];
        int pos = atomicAdd(&cur[v >> 20], 1);
        col[pos] = (int)(v & 0xFFFFF);
    }
}

// ---------- fused layer: y = relu(conv_nobias(gather(xin)) * inv_cnt + b) ----------
// One wave per node. Lane layout: p = lane&15 owns t = {8p..8p+7} (f16x8, 16B).
// Quarter-wave groups q = lane>>4 process 4 edges per load inst (1 KiB);
// packed fp16 accumulate; groups combined via xor-16/32 shuffles; fp32 epilogue.
__global__ void fused_layer_kernel(const f16x8* __restrict__ xin,   // [N*16]
                                   const int* __restrict__ offsets,
                                   const int* __restrict__ col,
                                   const float* __restrict__ inv_cnt,
                                   const float* __restrict__ w9,
                                   const float* __restrict__ bptr,
                                   f16x8* __restrict__ yout) {
    int tid = threadIdx.x;
    int lane = tid & 63;
    int q = lane >> 4;
    int p = lane & 15;
    int node = blockIdx.x * 4 + (tid >> 6);

    int lo = offsets[node], hi = offsets[node + 1];
    int cnt = hi - lo;
    int my_col = (lane < cnt) ? col[lo + lane] : 0;
    int jn = cnt < 64 ? cnt : 64;

    const f16 z = (f16)0;
    f16x8 acc0 = {z, z, z, z, z, z, z, z};
    f16x8 acc1 = {z, z, z, z, z, z, z, z};

    int j = 0;
    for (; j + 7 < jn; j += 8) {               // 8 edges / iter, 2 loads in flight
        int c0 = __shfl(my_col, j + q);
        int c1 = __shfl(my_col, j + 4 + q);
        f16x8 v0 = xin[(c0 << 4) | p];
        f16x8 v1 = xin[(c1 << 4) | p];
        acc0 += v0;
        acc1 += v1;
    }
    for (; j + 3 < jn; j += 4) {               // 4 edges
        int c = __shfl(my_col, j + q);
        acc0 += xin[(c << 4) | p];
    }
    if (j < jn) {                              // tail 1..3 edges
        int rem = jn - j;
        int c = __shfl(my_col, j + (q < rem ? q : 0));
        f16x8 v = xin[(c << 4) | p];
        if (q < rem) acc1 += v;
    }
    for (int k = 64; k < cnt; k++) {           // degree > 64 (effectively never)
        int c = col[lo + k];
        f16x8 v = xin[(c << 4) | p];
        if (q == 0) acc0 += v;
    }
    acc0 += acc1;

    // combine the 4 quarter-groups: xor-16 then xor-32 on the 16-byte acc
    {
        HU8 u; u.h = acc0;
        int4 o;
        o.x = __shfl_xor(u.i.x, 16); o.y = __shfl_xor(u.i.y, 16);
        o.z = __shfl_xor(u.i.z, 16); o.w = __shfl_xor(u.i.w, 16);
        HU8 w; w.i = o;
        acc0 += w.h;
        u.h = acc0;
        o.x = __shfl_xor(u.i.x, 32); o.y = __shfl_xor(u.i.y, 32);
        o.z = __shfl_xor(u.i.z, 32); o.w = __shfl_xor(u.i.w, 32);
        w.i = o;
        acc0 += w.h;
    }

    // fp32 epilogue: + self row, conv K=9, mean, bias, relu
    f16x8 sv = xin[(node << 4) | p];
    float A[16];   // A[0..3]=prev lane a[4..7], A[4..11]=own a[0..7], A[12..15]=next a[0..3]
    A[4]  = (float)acc0[0] + (float)sv[0];
    A[5]  = (float)acc0[1] + (float)sv[1];
    A[6]  = (float)acc0[2] + (float)sv[2];
    A[7]  = (float)acc0[3] + (float)sv[3];
    A[8]  = (float)acc0[4] + (float)sv[4];
    A[9]  = (float)acc0[5] + (float)sv[5];
    A[10] = (float)acc0[6] + (float)sv[6];
    A[11] = (float)acc0[7] + (float)sv[7];
#pragma unroll
    for (int i = 0; i < 4; i++) {
        A[i]      = __shfl_up(A[8 + i], 1, 16);    // prev lane's a[4..7]
        A[12 + i] = __shfl_down(A[4 + i], 1, 16);  // next lane's a[0..3]
    }
    if (p == 0)  { A[0] = 0.0f; A[1] = 0.0f; A[2] = 0.0f; A[3] = 0.0f; }
    if (p == 15) { A[12] = 0.0f; A[13] = 0.0f; A[14] = 0.0f; A[15] = 0.0f; }

    float wr[KK];
#pragma unroll
    for (int k = 0; k < KK; k++) wr[k] = w9[k];
    float ic = inv_cnt[node];
    float b = bptr[0];
    f16x8 o;
#pragma unroll
    for (int i = 0; i < 8; i++) {
        float s = 0.0f;
#pragma unroll
        for (int k = 0; k < KK; k++) s += wr[k] * A[i + k];
        s = fmaxf(s * ic + b, 0.0f);
        o[i] = (f16)s;
    }
    if (q == 0) yout[(node << 4) | p] = o;
}

// ---------- output head: out[t,c] = b[c] + sum_n y3flat[t*NN+n] * Wout[c*NN+n] ----------
// 196 blocks; block stages its 512-node Wout slice in LDS (Wout read once total),
// wave w handles t = w, w+4, ...; wave-reduce; atomicAdd into out.
__global__ void out_kernel(const f16* __restrict__ y3, const float* __restrict__ Wout,
                           const float* __restrict__ bout, float* __restrict__ out) {
    __shared__ float ws_w[OCH][4];
    int blk = blockIdx.x;
    int tid = threadIdx.x;
    int n0 = blk * OCH;
    int chunk = (n0 + OCH <= NN) ? OCH : (NN - n0);   // 512 or 160; both multiples of 4
    for (int i = tid; i < chunk; i += 256) {
        ws_w[i][0] = Wout[n0 + i];
        ws_w[i][1] = Wout[NN + n0 + i];
        ws_w[i][2] = Wout[2 * NN + n0 + i];
        ws_w[i][3] = 0.0f;
    }
    __syncthreads();
    int wave = tid >> 6;
    int lane = tid & 63;
    for (int t = wave; t < TT; t += 4) {
        float a0 = 0.0f, a1 = 0.0f, a2 = 0.0f;
        for (int base = lane * 4; base < chunk; base += 256) {
            f16x4 v = *(const f16x4*)(y3 + (size_t)t * NN + n0 + base);
#pragma unroll
            for (int k = 0; k < 4; k++) {
                float f = (float)v[k];
                a0 += f * ws_w[base + k][0];
                a1 += f * ws_w[base + k][1];
                a2 += f * ws_w[base + k][2];
            }
        }
        for (int o = 32; o > 0; o >>= 1) {
            a0 += __shfl_down(a0, o);
            a1 += __shfl_down(a1, o);
            a2 += __shfl_down(a2, o);
        }
        if (lane == 0) {
            if (blk == 0) { a0 += bout[0]; a1 += bout[1]; a2 += bout[2]; }
            atomicAdd(&out[t * 3 + 0], a0);
            atomicAdd(&out[t * 3 + 1], a1);
            atomicAdd(&out[t * 3 + 2], a2);
        }
    }
}

extern "C" void kernel_launch(void* const* d_in, const int* in_sizes, int n_in,
                              void* d_out, int out_size, void* d_ws, size_t ws_size,
                              hipStream_t stream) {
    const float* x    = (const float*)d_in[0];   // [N,T]
    const int*   ei   = (const int*)d_in[1];     // [2,E]
    const float* cw   = (const float*)d_in[2];   // [L,1,1,K]
    const float* cb   = (const float*)d_in[3];   // [L,1]
    const float* Wout = (const float*)d_in[4];   // [3,N]
    const float* bout = (const float*)d_in[5];   // [3]
    float* out = (float*)d_out;                  // [T,3]

    char* ws = (char*)d_ws;
    size_t off = 0;
    auto alloc = [&](size_t bytes) -> void* {
        void* p = ws + off;
        off += (bytes + 255) & ~(size_t)255;
        return p;
    };
    f16*          x16     = (f16*)alloc((size_t)NN * TT * 2);
    f16*          yA      = (f16*)alloc((size_t)NN * TT * 2);
    f16*          yB      = (f16*)alloc((size_t)NN * TT * 2);
    unsigned int* binned  = (unsigned int*)alloc((size_t)NBUCK * BCAP * 4);
    int*          gcursor = (int*)alloc((size_t)NBUCK * 4);
    int*          offsets = (int*)alloc((size_t)(NN + 1) * 4);
    float*        inv_cnt = (float*)alloc((size_t)NN * 4);
    int*          col     = (int*)alloc((size_t)EE * 4);

    // CSR build + cvt (per call — ws is re-poisoned before every launch)
    hipMemsetAsync(gcursor, 0, (size_t)NBUCK * 4, stream);
    bin_cvt_kernel<<<BINB + CVTB, 256, 0, stream>>>(ei, gcursor, binned,
                                                    (const float4*)x, (f16x4*)x16);
    bucket_csr_kernel<<<NBUCK, 256, 0, stream>>>(binned, gcursor, offsets, inv_cnt, col);

    // 3 fused layers (conv commuted past gather; bias/mean folded exactly)
    fused_layer_kernel<<<NN / 4, 256, 0, stream>>>((const f16x8*)x16, offsets, col, inv_cnt,
                                                   cw + 0 * KK, cb + 0, (f16x8*)yA);
    fused_layer_kernel<<<NN / 4, 256, 0, stream>>>((const f16x8*)yA, offsets, col, inv_cnt,
                                                   cw + 1 * KK, cb + 1, (f16x8*)yB);
    fused_layer_kernel<<<NN / 4, 256, 0, stream>>>((const f16x8*)yB, offsets, col, inv_cnt,
                                                   cw + 2 * KK, cb + 2, (f16x8*)yA);

    // output head (y3 = yA already has relu/mean applied)
    hipMemsetAsync(out, 0, (size_t)TT * 3 * 4, stream);
    out_kernel<<<ONB, 256, 0, stream>>>(yA, Wout, bout, out);
}

// Round 6
// 349.485 us; speedup vs baseline: 1.4676x; 1.4676x over previous
//
#include <hip/hip_runtime.h>

// Problem constants (match reference)
#define NN 100000
#define TT 128
#define EE 1600000
#define KK 9
#define PADK 4
#define NSPLIT 16                 // n-splits for output matmul (2048 blocks)

// Binned CSR build
#define BSH 7                     // 128 nodes per bucket
#define BMASK 127
#define NBUCK 782                 // ceil(100000/128)
#define BCAP 2560                 // avg 2046/bucket, sigma~45 -> 11 sigma headroom
#define BINB 782                  // (EE + 2047) / 2048
#define CVTB 12500                // NN*TT/4 / 256

typedef _Float16 f16;
typedef __attribute__((ext_vector_type(2))) _Float16 f16x2;
typedef __attribute__((ext_vector_type(4))) _Float16 f16x4;
typedef __attribute__((ext_vector_type(8))) _Float16 f16x8;

union HU8 { f16x8 h; int4 i; };

// ---------- fused: bin edges by dst range (blocks 0..BINB) + x fp32->fp16 (rest) ----------
// Packed edge: (dlocal << 20) | src   (src < 2^17, dlocal < 2^7)
__global__ void bin_cvt_kernel(const int* __restrict__ ei, int* __restrict__ gcursor,
                               unsigned int* __restrict__ binned,
                               const float4* __restrict__ x, f16x4* __restrict__ x16) {
    __shared__ int hist[NBUCK];
    __shared__ int gbase[NBUCK];
    int tid = threadIdx.x;

    if (blockIdx.x >= BINB) {
        // cvt part: one float4 per thread over N*T/4 (exactly CVTB*256 elements)
        int i = (blockIdx.x - BINB) * 256 + tid;
        float4 v = x[i];
        f16x4 o;
        o.x = (f16)v.x; o.y = (f16)v.y; o.z = (f16)v.z; o.w = (f16)v.w;
        x16[i] = o;
        return;
    }

    for (int i = tid; i < NBUCK; i += 256) hist[i] = 0;
    __syncthreads();
    int base = blockIdx.x * 2048;
    unsigned int val[8];
    int bkt[8];
    int rank[8];
#pragma unroll
    for (int k = 0; k < 8; k++) {
        int e = base + k * 256 + tid;
        bkt[k] = -1;
        if (e < EE) {
            int s = ei[e];            // src
            int d = ei[EE + e];       // dst
            bkt[k] = d >> BSH;
            val[k] = ((unsigned int)(d & BMASK) << 20) | (unsigned int)s;
            rank[k] = atomicAdd(&hist[bkt[k]], 1);
        }
    }
    __syncthreads();
    for (int i = tid; i < NBUCK; i += 256)
        gbase[i] = hist[i] ? atomicAdd(&gcursor[i], hist[i]) : 0;
    __syncthreads();
#pragma unroll
    for (int k = 0; k < 8; k++) {
        if (bkt[k] >= 0)
            binned[(size_t)bkt[k] * BCAP + gbase[bkt[k]] + rank[k]] = val[k];
    }
}

// ---------- scan bucket counts -> bucket bases (1 block; ~2 µs) ----------
__global__ void scanpart_kernel(const int* __restrict__ gcursor, int* __restrict__ part,
                                int* __restrict__ offsets) {
    __shared__ int sm[256];
    int tid = threadIdx.x;
    int base = tid * 4;
    int v[4];
    int s = 0;
#pragma unroll
    for (int k = 0; k < 4; k++) {
        int i = base + k;
        v[k] = (i < NBUCK) ? gcursor[i] : 0;
        s += v[k];
    }
    sm[tid] = s;
    __syncthreads();
    for (int off = 1; off < 256; off <<= 1) {
        int t = (tid >= off) ? sm[tid - off] : 0;
        __syncthreads();
        sm[tid] += t;
        __syncthreads();
    }
    int run = (tid == 0) ? 0 : sm[tid - 1];
#pragma unroll
    for (int k = 0; k < 4; k++) {
        int i = base + k;
        if (i < NBUCK) part[i] = run;
        run += v[k];
    }
    if (tid == 0) offsets[NN] = EE;
}

// ---------- per-bucket (128 nodes): hist + scan + offsets/inv_cnt + place ----------
__global__ void bucket_csr_kernel(const unsigned int* __restrict__ binned,
                                  const int* __restrict__ gcursor,
                                  const int* __restrict__ part,
                                  int* __restrict__ offsets,
                                  float* __restrict__ inv_cnt,
                                  int* __restrict__ col) {
    __shared__ int hist[128];
    __shared__ int cur[128];
    __shared__ int sc[128];
    int b = blockIdx.x;
    int tid = threadIdx.x;
    int cnt = gcursor[b];
    const unsigned int* ePtr = binned + (size_t)b * BCAP;
    if (tid < 128) hist[tid] = 0;
    __syncthreads();
    for (int j = tid; j < cnt; j += 256)
        atomicAdd(&hist[ePtr[j] >> 20], 1);
    __syncthreads();
    int d = (tid < 128) ? hist[tid] : 0;
    if (tid < 128) sc[tid] = d;
    __syncthreads();
    for (int off = 1; off < 128; off <<= 1) {
        int t = (tid < 128 && tid >= off) ? sc[tid - off] : 0;
        __syncthreads();
        if (tid < 128) sc[tid] += t;
        __syncthreads();
    }
    if (tid < 128) {
        int node = (b << BSH) + tid;
        int pos = part[b] + sc[tid] - d;   // exclusive prefix
        if (node < NN) {
            offsets[node] = pos;
            inv_cnt[node] = 1.0f / (1.0f + (float)d);
            cur[tid] = pos;
        }
    }
    __syncthreads();
    // place: all writes land in this bucket's contiguous col window (~8 KB, L2-resident)
    for (int j = tid; j < cnt; j += 256) {
        unsigned int v = ePtr[j];
        int pos = atomicAdd(&cur[v >> 20], 1);
        col[pos] = (int)(v & 0xFFFFF);
    }
}

// ---------- fused layer: y = relu(conv_nobias(gather(xin)) * inv_cnt + b) ----------
// One wave per node. Lane layout: p = lane&15 owns t = {8p..8p+7} (f16x8, 16B).
// Quarter-wave groups q = lane>>4 process 4 edges per load inst (1 KiB);
// packed fp16 accumulate; groups combined via xor-16/32 shuffles; fp32 epilogue.
__global__ void fused_layer_kernel(const f16x8* __restrict__ xin,   // [N*16]
                                   const int* __restrict__ offsets,
                                   const int* __restrict__ col,
                                   const float* __restrict__ inv_cnt,
                                   const float* __restrict__ w9,
                                   const float* __restrict__ bptr,
                                   f16x8* __restrict__ yout) {
    int tid = threadIdx.x;
    int lane = tid & 63;
    int q = lane >> 4;
    int p = lane & 15;
    int node = blockIdx.x * 4 + (tid >> 6);

    int lo = offsets[node], hi = offsets[node + 1];
    int cnt = hi - lo;
    int my_col = (lane < cnt) ? col[lo + lane] : 0;
    int jn = cnt < 64 ? cnt : 64;

    const f16 z = (f16)0;
    f16x8 acc0 = {z, z, z, z, z, z, z, z};
    f16x8 acc1 = {z, z, z, z, z, z, z, z};

    int j = 0;
    for (; j + 7 < jn; j += 8) {               // 8 edges / iter, 2 loads in flight
        int c0 = __shfl(my_col, j + q);
        int c1 = __shfl(my_col, j + 4 + q);
        f16x8 v0 = xin[(c0 << 4) | p];
        f16x8 v1 = xin[(c1 << 4) | p];
        acc0 += v0;
        acc1 += v1;
    }
    for (; j + 3 < jn; j += 4) {               // 4 edges
        int c = __shfl(my_col, j + q);
        acc0 += xin[(c << 4) | p];
    }
    if (j < jn) {                              // tail 1..3 edges
        int rem = jn - j;
        int c = __shfl(my_col, j + (q < rem ? q : 0));
        f16x8 v = xin[(c << 4) | p];
        if (q < rem) acc1 += v;
    }
    for (int k = 64; k < cnt; k++) {           // degree > 64 (effectively never)
        int c = col[lo + k];
        f16x8 v = xin[(c << 4) | p];
        if (q == 0) acc0 += v;
    }
    acc0 += acc1;

    // combine the 4 quarter-groups: xor-16 then xor-32 on the 16-byte acc
    {
        HU8 u; u.h = acc0;
        int4 o;
        o.x = __shfl_xor(u.i.x, 16); o.y = __shfl_xor(u.i.y, 16);
        o.z = __shfl_xor(u.i.z, 16); o.w = __shfl_xor(u.i.w, 16);
        HU8 w; w.i = o;
        acc0 += w.h;
        u.h = acc0;
        o.x = __shfl_xor(u.i.x, 32); o.y = __shfl_xor(u.i.y, 32);
        o.z = __shfl_xor(u.i.z, 32); o.w = __shfl_xor(u.i.w, 32);
        w.i = o;
        acc0 += w.h;
    }

    // fp32 epilogue: + self row, conv K=9, mean, bias, relu
    f16x8 sv = xin[(node << 4) | p];
    float A[16];   // A[0..3]=prev lane a[4..7], A[4..11]=own a[0..7], A[12..15]=next a[0..3]
    A[4]  = (float)acc0[0] + (float)sv[0];
    A[5]  = (float)acc0[1] + (float)sv[1];
    A[6]  = (float)acc0[2] + (float)sv[2];
    A[7]  = (float)acc0[3] + (float)sv[3];
    A[8]  = (float)acc0[4] + (float)sv[4];
    A[9]  = (float)acc0[5] + (float)sv[5];
    A[10] = (float)acc0[6] + (float)sv[6];
    A[11] = (float)acc0[7] + (float)sv[7];
#pragma unroll
    for (int i = 0; i < 4; i++) {
        A[i]      = __shfl_up(A[8 + i], 1, 16);    // prev lane's a[4..7]
        A[12 + i] = __shfl_down(A[4 + i], 1, 16);  // next lane's a[0..3]
    }
    if (p == 0)  { A[0] = 0.0f; A[1] = 0.0f; A[2] = 0.0f; A[3] = 0.0f; }
    if (p == 15) { A[12] = 0.0f; A[13] = 0.0f; A[14] = 0.0f; A[15] = 0.0f; }

    float wr[KK];
#pragma unroll
    for (int k = 0; k < KK; k++) wr[k] = w9[k];
    float ic = inv_cnt[node];
    float b = bptr[0];
    f16x8 o;
#pragma unroll
    for (int i = 0; i < 8; i++) {
        float s = 0.0f;
#pragma unroll
        for (int k = 0; k < KK; k++) s += wr[k] * A[i + k];
        s = fmaxf(s * ic + b, 0.0f);
        o[i] = (f16)s;
    }
    if (q == 0) yout[(node << 4) | p] = o;
}

// out[t,c] = b[c] + sum_n y3flat[t*NN + n] * Wout[c*NN + n]   (flat reinterpret view)
// (TT x NSPLIT) grid = 2048 blocks; Wout (1.2 MB) stays L2-resident; no LDS staging.
__global__ void out_kernel(const f16* __restrict__ y3, const float* __restrict__ Wout,
                           const float* __restrict__ bout, float* __restrict__ out) {
    int t = blockIdx.x;
    int sp = blockIdx.y;
    int tid = threadIdx.x;
    const int per = NN / NSPLIT;   // 6250
    int lo = sp * per;
    int hi = lo + per;
    float a0 = 0.0f, a1 = 0.0f, a2 = 0.0f;
    for (int n = lo + tid * 2; n < hi; n += 512) {
        f16x2 v2 = *(const f16x2*)(y3 + (size_t)t * NN + n);
        float vx = (float)v2.x, vy = (float)v2.y;
        float2 wA = *(const float2*)(Wout + n);
        float2 wB = *(const float2*)(Wout + NN + n);
        float2 wC = *(const float2*)(Wout + 2 * NN + n);
        a0 += vx * wA.x + vy * wA.y;
        a1 += vx * wB.x + vy * wB.y;
        a2 += vx * wC.x + vy * wC.y;
    }
    for (int o = 32; o > 0; o >>= 1) {
        a0 += __shfl_down(a0, o);
        a1 += __shfl_down(a1, o);
        a2 += __shfl_down(a2, o);
    }
    __shared__ float red[4][3];
    int wave = tid >> 6;
    if ((tid & 63) == 0) {
        red[wave][0] = a0;
        red[wave][1] = a1;
        red[wave][2] = a2;
    }
    __syncthreads();
    if (tid == 0) {
        float r0 = red[0][0] + red[1][0] + red[2][0] + red[3][0];
        float r1 = red[0][1] + red[1][1] + red[2][1] + red[3][1];
        float r2 = red[0][2] + red[1][2] + red[2][2] + red[3][2];
        if (sp == 0) {
            r0 += bout[0];
            r1 += bout[1];
            r2 += bout[2];
        }
        atomicAdd(&out[t * 3 + 0], r0);
        atomicAdd(&out[t * 3 + 1], r1);
        atomicAdd(&out[t * 3 + 2], r2);
    }
}

extern "C" void kernel_launch(void* const* d_in, const int* in_sizes, int n_in,
                              void* d_out, int out_size, void* d_ws, size_t ws_size,
                              hipStream_t stream) {
    const float* x    = (const float*)d_in[0];   // [N,T]
    const int*   ei   = (const int*)d_in[1];     // [2,E]
    const float* cw   = (const float*)d_in[2];   // [L,1,1,K]
    const float* cb   = (const float*)d_in[3];   // [L,1]
    const float* Wout = (const float*)d_in[4];   // [3,N]
    const float* bout = (const float*)d_in[5];   // [3]
    float* out = (float*)d_out;                  // [T,3]

    char* ws = (char*)d_ws;
    size_t off = 0;
    auto alloc = [&](size_t bytes) -> void* {
        void* p = ws + off;
        off += (bytes + 255) & ~(size_t)255;
        return p;
    };
    f16*          x16     = (f16*)alloc((size_t)NN * TT * 2);
    f16*          yA      = (f16*)alloc((size_t)NN * TT * 2);
    f16*          yB      = (f16*)alloc((size_t)NN * TT * 2);
    unsigned int* binned  = (unsigned int*)alloc((size_t)NBUCK * BCAP * 4);
    int*          gcursor = (int*)alloc((size_t)NBUCK * 4);
    int*          part    = (int*)alloc((size_t)NBUCK * 4);
    int*          offsets = (int*)alloc((size_t)(NN + 1) * 4);
    float*        inv_cnt = (float*)alloc((size_t)NN * 4);
    int*          col     = (int*)alloc((size_t)EE * 4);

    // CSR build + cvt (per call — ws is re-poisoned before every launch)
    hipMemsetAsync(gcursor, 0, (size_t)NBUCK * 4, stream);
    bin_cvt_kernel<<<BINB + CVTB, 256, 0, stream>>>(ei, gcursor, binned,
                                                    (const float4*)x, (f16x4*)x16);
    scanpart_kernel<<<1, 256, 0, stream>>>(gcursor, part, offsets);
    bucket_csr_kernel<<<NBUCK, 256, 0, stream>>>(binned, gcursor, part, offsets, inv_cnt, col);

    // 3 fused layers (conv commuted past gather; bias/mean folded exactly)
    fused_layer_kernel<<<NN / 4, 256, 0, stream>>>((const f16x8*)x16, offsets, col, inv_cnt,
                                                   cw + 0 * KK, cb + 0, (f16x8*)yA);
    fused_layer_kernel<<<NN / 4, 256, 0, stream>>>((const f16x8*)yA, offsets, col, inv_cnt,
                                                   cw + 1 * KK, cb + 1, (f16x8*)yB);
    fused_layer_kernel<<<NN / 4, 256, 0, stream>>>((const f16x8*)yB, offsets, col, inv_cnt,
                                                   cw + 2 * KK, cb + 2, (f16x8*)yA);

    // output head (y3 = yA already has relu/mean applied)
    hipMemsetAsync(out, 0, (size_t)TT * 3 * 4, stream);
    out_kernel<<<dim3(TT, NSPLIT), 256, 0, stream>>>(yA, Wout, bout, out);
}